// Round 1
// baseline (11193.159 us; speedup 1.0000x reference)
//
#include <hip/hip_runtime.h>

typedef unsigned short u16;
typedef __attribute__((ext_vector_type(8))) short s16x8;
typedef __attribute__((ext_vector_type(8))) u16 u16x8;
typedef __attribute__((ext_vector_type(4))) u16 u16x4;
typedef __attribute__((ext_vector_type(4))) float f32x4;
typedef __attribute__((ext_vector_type(2))) float f32x2;

__device__ __forceinline__ u16 f2bf(float f) {
  unsigned u = __builtin_bit_cast(unsigned, f);
  u = (u + 0x7fffu + ((u >> 16) & 1u)) >> 16;
  return (u16)u;
}
__device__ __forceinline__ float bf2f(u16 s) {
  unsigned u = ((unsigned)s) << 16;
  return __builtin_bit_cast(float, u);
}
__device__ __forceinline__ float sigmoidf_(float x) { return 1.f / (1.f + __expf(-x)); }
__device__ __forceinline__ float softplusf_(float x) { return (x > 20.f) ? x : logf(1.f + __expf(x)); }

__device__ __forceinline__ float wred_sum(float v) {
  #pragma unroll
  for (int d = 1; d < 64; d <<= 1) v += __shfl_xor(v, d);
  return v;
}
__device__ __forceinline__ float wred_max(float v) {
  #pragma unroll
  for (int d = 1; d < 64; d <<= 1) v = fmaxf(v, __shfl_xor(v, d));
  return v;
}

// ---------------- cast kernels ----------------
__global__ void castx_k(const float* __restrict__ in, u16* __restrict__ out, int n4) {
  int i = blockIdx.x * 256 + threadIdx.x;
  if (i < n4) {
    f32x4 v = *(const f32x4*)(in + (long)i * 4);
    u16x4 o;
    o.x = f2bf(v.x); o.y = f2bf(v.y); o.z = f2bf(v.z); o.w = f2bf(v.w);
    *(u16x4*)(out + (long)i * 4) = o;
  }
}

// f32 (K,N) row-major -> bf16 (N,K) row-major, batched over z
__global__ void castT_k(const float* __restrict__ in, u16* __restrict__ out, int K, int N) {
  long base = (long)blockIdx.z * K * N;
  int idx = blockIdx.x * 256 + threadIdx.x;
  if (idx < K * N) {
    int n = idx / K, k = idx - n * K;
    out[base + idx] = f2bf(in[base + (long)k * N + n]);
  }
}

// extract transposed V: vT[(b,h)][d][s] = qkv[(b,s)][2H + h*64 + d]
__global__ void vtx_k(const u16* __restrict__ qkv, u16* __restrict__ vT) {
  int idx = blockIdx.x * 256 + threadIdx.x;   // 0 .. 2097151
  int s = idx & 511;
  int d = (idx >> 9) & 63;
  int bh = idx >> 15;
  int b = bh >> 3, h = bh & 7;
  vT[idx] = qkv[((long)(b * 512 + s)) * 1536 + 1024 + h * 64 + d];
}

// ---------------- GEMM (bf16 MFMA, B passed as B^T = (N,K) row-major) ----------------
struct GemmP {
  const u16* A; const u16* B; const float* bias;
  float* outF; u16* outB;
  int M, N, K, lda, ldb, ldc;
  long sAb, sAh, sAz, sBb, sBh, sBz, sCb, sCh, sCz;
  int zdiv, z0;
  float alpha; int relu;
};

__global__ __launch_bounds__(256) void gemm_k(GemmP p) {
  __shared__ u16 sA[128 * 72];
  __shared__ u16 sB[128 * 72];
  int tid = threadIdx.x;
  int gp = p.z0 + blockIdx.z;
  int zb = gp / p.zdiv, zh = gp - zb * p.zdiv;
  const u16* Ab = p.A + zb * p.sAb + zh * p.sAh + (long)blockIdx.z * p.sAz + (long)blockIdx.x * 128 * p.lda;
  const u16* Bb = p.B + zb * p.sBb + zh * p.sBh + (long)blockIdx.z * p.sBz;
  long coff = zb * p.sCb + zh * p.sCh + (long)blockIdx.z * p.sCz;
  int bn = blockIdx.y * 128;
  int lane = tid & 63, wid = tid >> 6;
  int wr = wid >> 1, wc = wid & 1;

  f32x4 acc[4][4];
  f32x4 z4 = {0.f, 0.f, 0.f, 0.f};
  #pragma unroll
  for (int i = 0; i < 4; i++)
    #pragma unroll
    for (int j = 0; j < 4; j++) acc[i][j] = z4;

  int r = tid >> 1, c32 = (tid & 1) * 32;
  for (int k0 = 0; k0 < p.K; k0 += 64) {
    const u16* Ag = Ab + (long)r * p.lda + k0 + c32;
    u16x8* dA = (u16x8*)(sA + r * 72 + c32);
    #pragma unroll
    for (int i = 0; i < 4; i++) dA[i] = *(const u16x8*)(Ag + i * 8);
    int nrow = bn + r;
    u16x8* dB = (u16x8*)(sB + r * 72 + c32);
    if (nrow < p.N) {
      const u16* Bg = Bb + (long)nrow * p.ldb + k0 + c32;
      #pragma unroll
      for (int i = 0; i < 4; i++) dB[i] = *(const u16x8*)(Bg + i * 8);
    } else {
      u16x8 zz = (u16x8)0;
      #pragma unroll
      for (int i = 0; i < 4; i++) dB[i] = zz;
    }
    __syncthreads();
    #pragma unroll
    for (int ks = 0; ks < 2; ks++) {
      int ko = ks * 32 + (lane >> 4) * 8;
      s16x8 af[4], bf[4];
      #pragma unroll
      for (int m = 0; m < 4; m++) af[m] = *(const s16x8*)(sA + (wr * 64 + m * 16 + (lane & 15)) * 72 + ko);
      #pragma unroll
      for (int n = 0; n < 4; n++) bf[n] = *(const s16x8*)(sB + (wc * 64 + n * 16 + (lane & 15)) * 72 + ko);
      #pragma unroll
      for (int m = 0; m < 4; m++)
        #pragma unroll
        for (int n = 0; n < 4; n++)
          acc[m][n] = __builtin_amdgcn_mfma_f32_16x16x32_bf16(af[m], bf[n], acc[m][n], 0, 0, 0);
    }
    __syncthreads();
  }

  int row0 = blockIdx.x * 128 + wr * 64;
  int col0 = bn + wc * 64;
  #pragma unroll
  for (int n = 0; n < 4; n++) {
    int col = col0 + n * 16 + (lane & 15);
    if (col >= p.N) continue;
    float bv = p.bias ? p.bias[col] : 0.f;
    #pragma unroll
    for (int m = 0; m < 4; m++) {
      #pragma unroll
      for (int q = 0; q < 4; q++) {
        int row = row0 + m * 16 + (lane >> 4) * 4 + q;
        float v = acc[m][n][q] * p.alpha + bv;
        if (p.relu) v = fmaxf(v, 0.f);
        long ci = coff + (long)row * p.ldc + col;
        if (p.outF) p.outF[ci] = v;
        if (p.outB) p.outB[ci] = f2bf(v);
      }
    }
  }
}

// ---------------- fused residual + LayerNorm ----------------
__global__ __launch_bounds__(64) void ln_k(const float* __restrict__ a, const float* __restrict__ res,
                                           const float* __restrict__ g, const float* __restrict__ bb,
                                           float* __restrict__ outF, u16* __restrict__ outB) {
  int row = blockIdx.x, t = threadIdx.x;
  const float* ar = a + (long)row * 512;
  const float* rr = res + (long)row * 512;
  float x[8];
  float s1 = 0.f;
  #pragma unroll
  for (int i = 0; i < 8; i++) { x[i] = ar[i * 64 + t] + rr[i * 64 + t]; s1 += x[i]; }
  s1 = wred_sum(s1);
  float mean = s1 * (1.f / 512.f);
  float s2 = 0.f;
  #pragma unroll
  for (int i = 0; i < 8; i++) { float d = x[i] - mean; s2 += d * d; }
  s2 = wred_sum(s2);
  float inv = rsqrtf(s2 * (1.f / 512.f) + 1e-5f);
  #pragma unroll
  for (int i = 0; i < 8; i++) {
    int cc = i * 64 + t;
    float y = (x[i] - mean) * inv * g[cc] + bb[cc];
    outF[(long)row * 512 + cc] = y;
    outB[(long)row * 512 + cc] = f2bf(y);
  }
}

// ---------------- row softmax (512 cols) -> bf16 ----------------
__global__ __launch_bounds__(64) void smax_k(const float* __restrict__ s, u16* __restrict__ p) {
  long row = blockIdx.x;
  const float* sr = s + row * 512;
  int t = threadIdx.x;
  float v[8];
  float mx = -1e30f;
  #pragma unroll
  for (int i = 0; i < 8; i++) { v[i] = sr[i * 64 + t]; mx = fmaxf(mx, v[i]); }
  mx = wred_max(mx);
  float se = 0.f;
  #pragma unroll
  for (int i = 0; i < 8; i++) { v[i] = __expf(v[i] - mx); se += v[i]; }
  se = wred_sum(se);
  float inv = 1.f / se;
  u16* pr = p + row * 512;
  #pragma unroll
  for (int i = 0; i < 8; i++) pr[i * 64 + t] = f2bf(v[i] * inv);
}

// ---------------- DNC memory scan ----------------
// one block per batch; thread n owns M row n in registers (64 f32)
#define SCAN_LDS 156064
__global__ __launch_bounds__(1024) void scan_k(const float* __restrict__ iface,
                                               const float* __restrict__ M0,
                                               float* __restrict__ out) {
  int b = blockIdx.x, tid = threadIdx.x, lane = tid & 63, wid = tid >> 6;
  extern __shared__ char smem[];
  float* s_aux  = (float*)smem;          // 32: [0]=inv|wk|, [1..8]=inv|rk_h|, [9]=1/wtot, [10]=wb, [11]=gw, [12..19]=rb
  float* s_red  = s_aux + 32;            // 128
  float* s_tot  = s_red + 128;           // 8
  float* s_er   = s_tot + 8;             // 64 (sigmoid applied)
  float* s_wv   = s_er + 64;             // 64
  float* s_wk   = s_wv + 64;             // 64 (raw)
  float* s_rk   = s_wk + 64;             // 512 (raw)
  float* s_comb = s_rk + 512;            // 1024
  u16*   s_rw   = (u16*)(s_comb + 1024); // 8*1024 bf16 (unnormalized exp)
  float* s_Mf   = (float*)(s_rw + 8192); // 64 * 516 f32 chunk

  float m[64];
  {
    const float* M0r = M0 + (long)tid * 64;
    #pragma unroll
    for (int i = 0; i < 16; i++) {
      f32x4 v = *(const f32x4*)(M0r + i * 4);
      m[i * 4 + 0] = v.x; m[i * 4 + 1] = v.y; m[i * 4 + 2] = v.z; m[i * 4 + 3] = v.w;
    }
  }
  const float* ifb = iface + (long)b * 512 * 714;
  float* outb = out + (long)b * 512 * 512;
  int o9 = tid & 511, sub = tid >> 9;
  int oh = o9 >> 6, ow = o9 & 63;

  for (int t = 0; t < 512; ++t) {
    const float* ro = ifb + (long)t * 714;
    __syncthreads();
    // stage interface row + norms
    if (wid == 0) {
      float aa = ro[520 + lane];
      s_wk[lane] = aa;
      float ss = wred_sum(aa * aa);
      if (lane == 0) s_aux[0] = rsqrtf(ss + 1e-8f);
    } else if (wid <= 8) {
      int h = wid - 1;
      float aa = ro[h * 64 + lane];
      s_rk[h * 64 + lane] = aa;
      float ss = wred_sum(aa * aa);
      if (lane == 0) s_aux[1 + h] = rsqrtf(ss + 1e-8f);
    } else if (wid == 9) {
      s_er[lane] = sigmoidf_(ro[585 + lane]);
    } else if (wid == 10) {
      s_wv[lane] = ro[649 + lane];
    } else if (wid == 11) {
      if (lane < 8)       s_aux[12 + lane] = softplusf_(ro[512 + lane]);
      else if (lane == 8) s_aux[10] = softplusf_(ro[584]);
      else if (lane == 9) s_aux[11] = sigmoidf_(ro[713]);
    }
    __syncthreads();

    // ---- phase A: write addressing ----
    float n2 = 1e-8f;
    #pragma unroll
    for (int w = 0; w < 64; w++) n2 = __builtin_fmaf(m[w], m[w], n2);
    float invm = rsqrtf(n2);
    float dot = 0.f;
    #pragma unroll
    for (int w4 = 0; w4 < 16; w4++) {
      f32x4 kk = *(const f32x4*)(s_wk + w4 * 4);
      dot = __builtin_fmaf(kk.x, m[w4 * 4 + 0], dot);
      dot = __builtin_fmaf(kk.y, m[w4 * 4 + 1], dot);
      dot = __builtin_fmaf(kk.z, m[w4 * 4 + 2], dot);
      dot = __builtin_fmaf(kk.w, m[w4 * 4 + 3], dot);
    }
    float ew = __expf(s_aux[10] * (dot * invm * s_aux[0]));
    float ssum = wred_sum(ew);
    if (lane == 0) s_red[wid] = ssum;
    __syncthreads();
    if (tid == 0) {
      float tt = 0.f;
      #pragma unroll
      for (int i = 0; i < 16; i++) tt += s_red[i];
      s_aux[9] = 1.f / tt;
    }
    __syncthreads();
    float ww = s_aux[11] * ew * s_aux[9];

    // ---- phase B: memory update ----
    #pragma unroll
    for (int w4 = 0; w4 < 16; w4++) {
      f32x4 ev = *(const f32x4*)(s_er + w4 * 4);
      f32x4 vv = *(const f32x4*)(s_wv + w4 * 4);
      #pragma unroll
      for (int c = 0; c < 4; c++) {
        int w = w4 * 4 + c;
        float aa = __builtin_fmaf(-ev[c], m[w], vv[c]);
        m[w] = __builtin_fmaf(ww, aa, m[w]);
      }
    }

    // ---- phase C: read addressing ----
    n2 = 1e-8f;
    #pragma unroll
    for (int w = 0; w < 64; w++) n2 = __builtin_fmaf(m[w], m[w], n2);
    invm = rsqrtf(n2);
    float eh[8];
    #pragma unroll
    for (int h = 0; h < 8; h++) {
      float dh = 0.f;
      #pragma unroll
      for (int w4 = 0; w4 < 16; w4++) {
        f32x4 kk = *(const f32x4*)(s_rk + h * 64 + w4 * 4);
        dh = __builtin_fmaf(kk.x, m[w4 * 4 + 0], dh);
        dh = __builtin_fmaf(kk.y, m[w4 * 4 + 1], dh);
        dh = __builtin_fmaf(kk.z, m[w4 * 4 + 2], dh);
        dh = __builtin_fmaf(kk.w, m[w4 * 4 + 3], dh);
      }
      eh[h] = __expf(s_aux[12 + h] * (dh * invm * s_aux[1 + h]));
      s_rw[h * 1024 + tid] = f2bf(eh[h]);
    }
    #pragma unroll
    for (int h = 0; h < 8; h++) {
      float sh = wred_sum(eh[h]);
      if (lane == 0) s_red[wid * 8 + h] = sh;
    }
    __syncthreads();
    if (tid < 8) {
      float tt = 0.f;
      #pragma unroll
      for (int i = 0; i < 16; i++) tt += s_red[i * 8 + tid];
      s_tot[tid] = 1.f / tt;
    }

    // ---- phase D: weighted read, 2 chunks of 512 rows through LDS ----
    float acc = 0.f;
    #pragma unroll 1
    for (int cc = 0; cc < 2; cc++) {
      __syncthreads();
      if (sub == cc) {
        int nn = o9;
        #pragma unroll
        for (int w = 0; w < 64; w++) s_Mf[w * 516 + nn] = m[w];
      }
      __syncthreads();
      const f32x4* Mr = (const f32x4*)(s_Mf + ow * 516 + sub * 256);
      const u16x4* rp = (const u16x4*)(s_rw + oh * 1024 + cc * 512 + sub * 256);
      #pragma unroll 4
      for (int j = 0; j < 64; j++) {
        f32x4 mv = Mr[j];
        u16x4 rv = rp[j];
        acc = __builtin_fmaf(mv.x, bf2f(rv.x), acc);
        acc = __builtin_fmaf(mv.y, bf2f(rv.y), acc);
        acc = __builtin_fmaf(mv.z, bf2f(rv.z), acc);
        acc = __builtin_fmaf(mv.w, bf2f(rv.w), acc);
      }
    }
    __syncthreads();
    s_comb[tid] = acc;
    __syncthreads();
    if (tid < 512) {
      float rr = (s_comb[tid] + s_comb[tid + 512]) * s_tot[tid >> 6];
      outb[(long)t * 512 + tid] = rr;
    }
  }
}

// ---------------- host ----------------
static void launch_gemm(hipStream_t stream, const u16* A, int lda, const u16* B, int ldb,
                        const float* bias, float* oF, u16* oB, int ldc,
                        int M, int N, int K, int gz,
                        long sAb, long sAh, long sAz, long sBb, long sBh, long sBz,
                        long sCb, long sCh, long sCz, int zdiv, int z0, float alpha, int relu) {
  GemmP p;
  p.A = A; p.B = B; p.bias = bias; p.outF = oF; p.outB = oB;
  p.M = M; p.N = N; p.K = K; p.lda = lda; p.ldb = ldb; p.ldc = ldc;
  p.sAb = sAb; p.sAh = sAh; p.sAz = sAz;
  p.sBb = sBb; p.sBh = sBh; p.sBz = sBz;
  p.sCb = sCb; p.sCh = sCh; p.sCz = sCz;
  p.zdiv = zdiv; p.z0 = z0; p.alpha = alpha; p.relu = relu;
  dim3 g(M / 128, (N + 127) / 128, gz);
  gemm_k<<<g, 256, 0, stream>>>(p);
}

extern "C" void kernel_launch(void* const* d_in, const int* in_sizes, int n_in,
                              void* d_out, int out_size, void* d_ws, size_t ws_size,
                              hipStream_t stream) {
  (void)in_sizes; (void)n_in; (void)out_size; (void)ws_size;
  const float* x    = (const float*)d_in[0];
  const float* Wp   = (const float*)d_in[1];
  const float* bp   = (const float*)d_in[2];
  const float* Wqkv = (const float*)d_in[3];
  const float* bqkv = (const float*)d_in[4];
  const float* Wo   = (const float*)d_in[5];
  const float* bo   = (const float*)d_in[6];
  const float* ln1g = (const float*)d_in[7];
  const float* ln1b = (const float*)d_in[8];
  const float* W1   = (const float*)d_in[9];
  const float* b1   = (const float*)d_in[10];
  const float* W2   = (const float*)d_in[11];
  const float* b2   = (const float*)d_in[12];
  const float* ln2g = (const float*)d_in[13];
  const float* ln2b = (const float*)d_in[14];
  const float* Wi   = (const float*)d_in[15];
  const float* bi   = (const float*)d_in[16];
  const float* M0   = (const float*)d_in[17];
  float* outF = (float*)d_out;

  char* ws = (char*)d_ws;
  u16* WpT   = (u16*)ws;
  u16* WqkvT = WpT + 262144;
  u16* WoT   = WqkvT + 1572864;
  u16* W1T   = WoT + 524288;
  u16* W2T   = W1T + 2097152;
  u16* WiT   = W2T + 2097152;
  u16* xb    = WiT + 365568;
  u16* hb    = xb + 2097152;
  float* h   = (float*)(hb + 2097152);
  u16* qkvb  = (u16*)(h + 2097152);
  u16* vT    = qkvb + 6291456;
  float* scores = (float*)(vT + 2097152);
  u16* pbuf  = (u16*)(scores + 4194304);
  u16* obuf  = pbuf + 4194304;
  float* gout = (float*)(obuf + 2097152);
  u16* ffb   = (u16*)(gout + 2924544);
  float* ifbuf = (float*)(ffb + 8388608);

  // casts / transposes
  castx_k<<<2048, 256, 0, stream>>>(x, xb, 524288);
  castT_k<<<dim3(1024, 1, 1), 256, 0, stream>>>(Wp, WpT, 512, 512);
  castT_k<<<dim3(3072, 1, 2), 256, 0, stream>>>(Wqkv, WqkvT, 512, 1536);
  castT_k<<<dim3(1024, 1, 2), 256, 0, stream>>>(Wo, WoT, 512, 512);
  castT_k<<<dim3(4096, 1, 2), 256, 0, stream>>>(W1, W1T, 512, 2048);
  castT_k<<<dim3(4096, 1, 2), 256, 0, stream>>>(W2, W2T, 2048, 512);
  castT_k<<<dim3(1428, 1, 1), 256, 0, stream>>>(Wi, WiT, 512, 714);

  // projection: h = x @ Wp + bp
  launch_gemm(stream, xb, 512, WpT, 512, bp, h, hb, 512, 4096, 512, 512,
              1, 0,0,0, 0,0,0, 0,0,0, 1, 0, 1.f, 0);

  for (int l = 0; l < 2; ++l) {
    // qkv = h @ Wqkv[l] + bqkv[l]
    launch_gemm(stream, hb, 512, WqkvT + (long)l * 786432, 512, bqkv + l * 1536,
                nullptr, qkvb, 1536, 4096, 1536, 512,
                1, 0,0,0, 0,0,0, 0,0,0, 1, 0, 1.f, 0);
    vtx_k<<<8192, 256, 0, stream>>>(qkvb, vT);
    for (int ch = 0; ch < 4; ++ch) {
      // scores = q @ k^T * 0.125
      launch_gemm(stream, qkvb, 1536, qkvb + 512, 1536, nullptr, scores, nullptr, 512,
                  512, 512, 64, 16,
                  786432, 64, 0,  786432, 64, 0,  0, 0, 262144, 8, ch * 16, 0.125f, 0);
      smax_k<<<8192, 64, 0, stream>>>(scores, pbuf);
      // o = p @ v
      launch_gemm(stream, pbuf, 512, vT, 512, nullptr, nullptr, obuf, 512,
                  512, 64, 512, 16,
                  0, 0, 262144,  262144, 32768, 0,  262144, 64, 0, 8, ch * 16, 1.f, 0);
    }
    // o @ Wo + bo -> gout
    launch_gemm(stream, obuf, 512, WoT + (long)l * 262144, 512, bo + l * 512,
                gout, nullptr, 512, 4096, 512, 512,
                1, 0,0,0, 0,0,0, 0,0,0, 1, 0, 1.f, 0);
    ln_k<<<4096, 64, 0, stream>>>(gout, h, ln1g + l * 512, ln1b + l * 512, h, hb);
    // ff1 = relu(h @ W1 + b1)
    launch_gemm(stream, hb, 512, W1T + (long)l * 1048576, 512, b1 + l * 2048,
                nullptr, ffb, 2048, 4096, 2048, 512,
                1, 0,0,0, 0,0,0, 0,0,0, 1, 0, 1.f, 1);
    // ff2 = ff1 @ W2 + b2 -> gout
    launch_gemm(stream, ffb, 2048, W2T + (long)l * 1048576, 2048, b2 + l * 512,
                gout, nullptr, 512, 4096, 512, 2048,
                1, 0,0,0, 0,0,0, 0,0,0, 1, 0, 1.f, 0);
    float* lnout = (l == 1) ? outF : h;
    ln_k<<<4096, 64, 0, stream>>>(gout, h, ln2g + l * 512, ln2b + l * 512, lnout, hb);
  }

  // iface = tout @ Wi + bi
  launch_gemm(stream, hb, 512, WiT, 512, bi, ifbuf, nullptr, 714,
              4096, 714, 512, 1, 0,0,0, 0,0,0, 0,0,0, 1, 0, 1.f, 0);

  // DNC scan
  hipFuncSetAttribute(reinterpret_cast<const void*>(scan_k),
                      hipFuncAttributeMaxDynamicSharedMemorySize, SCAN_LDS);
  scan_k<<<8, 1024, SCAN_LDS, stream>>>(ifbuf, M0, outF + 2097152);
}

// Round 2
// 3706.544 us; speedup vs baseline: 3.0198x; 3.0198x over previous
//
#include <hip/hip_runtime.h>

typedef unsigned short u16;
typedef unsigned int u32;
typedef __attribute__((ext_vector_type(8))) short s16x8;
typedef __attribute__((ext_vector_type(8))) u16 u16x8;
typedef __attribute__((ext_vector_type(4))) u16 u16x4;
typedef __attribute__((ext_vector_type(4))) u32 u32x4;
typedef __attribute__((ext_vector_type(4))) float f32x4;
typedef __attribute__((ext_vector_type(2))) float f32x2;

__device__ __forceinline__ u16 f2bf(float f) {
  unsigned u = __builtin_bit_cast(unsigned, f);
  u = (u + 0x7fffu + ((u >> 16) & 1u)) >> 16;
  return (u16)u;
}
__device__ __forceinline__ float bf2f(u16 s) {
  unsigned u = ((unsigned)s) << 16;
  return __builtin_bit_cast(float, u);
}
__device__ __forceinline__ float blo(u32 d) { return __builtin_bit_cast(float, d << 16); }
__device__ __forceinline__ float bhi(u32 d) { return __builtin_bit_cast(float, d & 0xFFFF0000u); }
__device__ __forceinline__ float sigmoidf_(float x) { return 1.f / (1.f + __expf(-x)); }
__device__ __forceinline__ float softplusf_(float x) { return (x > 20.f) ? x : logf(1.f + __expf(x)); }

__device__ __forceinline__ float wred_sum(float v) {
  #pragma unroll
  for (int d = 1; d < 64; d <<= 1) v += __shfl_xor(v, d);
  return v;
}
__device__ __forceinline__ float wred_max(float v) {
  #pragma unroll
  for (int d = 1; d < 64; d <<= 1) v = fmaxf(v, __shfl_xor(v, d));
  return v;
}

// ---------------- cast kernels ----------------
__global__ void castx_k(const float* __restrict__ in, u16* __restrict__ out, int n4) {
  int i = blockIdx.x * 256 + threadIdx.x;
  if (i < n4) {
    f32x4 v = *(const f32x4*)(in + (long)i * 4);
    u16x4 o;
    o.x = f2bf(v.x); o.y = f2bf(v.y); o.z = f2bf(v.z); o.w = f2bf(v.w);
    *(u16x4*)(out + (long)i * 4) = o;
  }
}

// f32 (K,N) row-major -> bf16 (N,K) row-major, batched over z
__global__ void castT_k(const float* __restrict__ in, u16* __restrict__ out, int K, int N) {
  long base = (long)blockIdx.z * K * N;
  int idx = blockIdx.x * 256 + threadIdx.x;
  if (idx < K * N) {
    int n = idx / K, k = idx - n * K;
    out[base + idx] = f2bf(in[base + (long)k * N + n]);
  }
}

// extract transposed V: vT[(b,h)][d][s] = qkv[(b,s)][2H + h*64 + d]
__global__ void vtx_k(const u16* __restrict__ qkv, u16* __restrict__ vT) {
  int idx = blockIdx.x * 256 + threadIdx.x;
  int s = idx & 511;
  int d = (idx >> 9) & 63;
  int bh = idx >> 15;
  int b = bh >> 3, h = bh & 7;
  vT[idx] = qkv[((long)(b * 512 + s)) * 1536 + 1024 + h * 64 + d];
}

// ---------------- GEMM (bf16 MFMA, B passed as B^T = (N,K) row-major) ----------------
struct GemmP {
  const u16* A; const u16* B; const float* bias;
  float* outF; u16* outB;
  int M, N, K, lda, ldb, ldc;
  long sAb, sAh, sAz, sBb, sBh, sBz, sCb, sCh, sCz;
  int zdiv, z0;
  float alpha; int relu;
};

__global__ __launch_bounds__(256) void gemm_k(GemmP p) {
  __shared__ u16 sA[128 * 72];
  __shared__ u16 sB[128 * 72];
  int tid = threadIdx.x;
  int gp = p.z0 + blockIdx.z;
  int zb = gp / p.zdiv, zh = gp - zb * p.zdiv;
  const u16* Ab = p.A + zb * p.sAb + zh * p.sAh + (long)blockIdx.z * p.sAz + (long)blockIdx.x * 128 * p.lda;
  const u16* Bb = p.B + zb * p.sBb + zh * p.sBh + (long)blockIdx.z * p.sBz;
  long coff = zb * p.sCb + zh * p.sCh + (long)blockIdx.z * p.sCz;
  int bn = blockIdx.y * 128;
  int lane = tid & 63, wid = tid >> 6;
  int wr = wid >> 1, wc = wid & 1;

  f32x4 acc[4][4];
  f32x4 z4 = {0.f, 0.f, 0.f, 0.f};
  #pragma unroll
  for (int i = 0; i < 4; i++)
    #pragma unroll
    for (int j = 0; j < 4; j++) acc[i][j] = z4;

  int r = tid >> 1, c32 = (tid & 1) * 32;
  for (int k0 = 0; k0 < p.K; k0 += 64) {
    const u16* Ag = Ab + (long)r * p.lda + k0 + c32;
    u16x8* dA = (u16x8*)(sA + r * 72 + c32);
    #pragma unroll
    for (int i = 0; i < 4; i++) dA[i] = *(const u16x8*)(Ag + i * 8);
    int nrow = bn + r;
    u16x8* dB = (u16x8*)(sB + r * 72 + c32);
    if (nrow < p.N) {
      const u16* Bg = Bb + (long)nrow * p.ldb + k0 + c32;
      #pragma unroll
      for (int i = 0; i < 4; i++) dB[i] = *(const u16x8*)(Bg + i * 8);
    } else {
      u16x8 zz = (u16x8)0;
      #pragma unroll
      for (int i = 0; i < 4; i++) dB[i] = zz;
    }
    __syncthreads();
    #pragma unroll
    for (int ks = 0; ks < 2; ks++) {
      int ko = ks * 32 + (lane >> 4) * 8;
      s16x8 af[4], bf[4];
      #pragma unroll
      for (int m = 0; m < 4; m++) af[m] = *(const s16x8*)(sA + (wr * 64 + m * 16 + (lane & 15)) * 72 + ko);
      #pragma unroll
      for (int n = 0; n < 4; n++) bf[n] = *(const s16x8*)(sB + (wc * 64 + n * 16 + (lane & 15)) * 72 + ko);
      #pragma unroll
      for (int m = 0; m < 4; m++)
        #pragma unroll
        for (int n = 0; n < 4; n++)
          acc[m][n] = __builtin_amdgcn_mfma_f32_16x16x32_bf16(af[m], bf[n], acc[m][n], 0, 0, 0);
    }
    __syncthreads();
  }

  int row0 = blockIdx.x * 128 + wr * 64;
  int col0 = bn + wc * 64;
  #pragma unroll
  for (int n = 0; n < 4; n++) {
    int col = col0 + n * 16 + (lane & 15);
    if (col >= p.N) continue;
    float bv = p.bias ? p.bias[col] : 0.f;
    #pragma unroll
    for (int m = 0; m < 4; m++) {
      #pragma unroll
      for (int q = 0; q < 4; q++) {
        int row = row0 + m * 16 + (lane >> 4) * 4 + q;
        float v = acc[m][n][q] * p.alpha + bv;
        if (p.relu) v = fmaxf(v, 0.f);
        long ci = coff + (long)row * p.ldc + col;
        if (p.outF) p.outF[ci] = v;
        if (p.outB) p.outB[ci] = f2bf(v);
      }
    }
  }
}

// ---------------- fused residual + LayerNorm ----------------
__global__ __launch_bounds__(64) void ln_k(const float* __restrict__ a, const float* __restrict__ res,
                                           const float* __restrict__ g, const float* __restrict__ bb,
                                           float* __restrict__ outF, u16* __restrict__ outB) {
  int row = blockIdx.x, t = threadIdx.x;
  const float* ar = a + (long)row * 512;
  const float* rr = res + (long)row * 512;
  float x[8];
  float s1 = 0.f;
  #pragma unroll
  for (int i = 0; i < 8; i++) { x[i] = ar[i * 64 + t] + rr[i * 64 + t]; s1 += x[i]; }
  s1 = wred_sum(s1);
  float mean = s1 * (1.f / 512.f);
  float s2 = 0.f;
  #pragma unroll
  for (int i = 0; i < 8; i++) { float d = x[i] - mean; s2 += d * d; }
  s2 = wred_sum(s2);
  float inv = rsqrtf(s2 * (1.f / 512.f) + 1e-5f);
  #pragma unroll
  for (int i = 0; i < 8; i++) {
    int cc = i * 64 + t;
    float y = (x[i] - mean) * inv * g[cc] + bb[cc];
    outF[(long)row * 512 + cc] = y;
    outB[(long)row * 512 + cc] = f2bf(y);
  }
}

// ---------------- row softmax (512 cols) -> bf16 ----------------
__global__ __launch_bounds__(64) void smax_k(const float* __restrict__ s, u16* __restrict__ p) {
  long row = blockIdx.x;
  const float* sr = s + row * 512;
  int t = threadIdx.x;
  float v[8];
  float mx = -1e30f;
  #pragma unroll
  for (int i = 0; i < 8; i++) { v[i] = sr[i * 64 + t]; mx = fmaxf(mx, v[i]); }
  mx = wred_max(mx);
  float se = 0.f;
  #pragma unroll
  for (int i = 0; i < 8; i++) { v[i] = __expf(v[i] - mx); se += v[i]; }
  se = wred_sum(se);
  float inv = 1.f / se;
  u16* pr = p + row * 512;
  #pragma unroll
  for (int i = 0; i < 8; i++) pr[i * 64 + t] = f2bf(v[i] * inv);
}

// ---------------- DNC pass 1: sequential write-path scan ----------------
// 8 blocks (one per batch), 1024 threads, thread n owns M row n (64 f32 regs).
// Emits ww[b][t][n] (f32) and bf16 M snapshots every 16 steps.
__global__ __launch_bounds__(1024) void scan1_k(const float* __restrict__ iface,
                                                const float* __restrict__ M0,
                                                float* __restrict__ ww_out,
                                                u16* __restrict__ snap) {
  int b = blockIdx.x, tid = threadIdx.x, lane = tid & 63, wid = tid >> 6;
  __shared__ float s_wk[64], s_er[64], s_wv[64], s_aux[4], s_red[16];
  float m[64];
  {
    const float* M0r = M0 + (long)tid * 64;
    #pragma unroll
    for (int i = 0; i < 16; i++) {
      f32x4 v = *(const f32x4*)(M0r + i * 4);
      m[i * 4 + 0] = v.x; m[i * 4 + 1] = v.y; m[i * 4 + 2] = v.z; m[i * 4 + 3] = v.w;
    }
  }
  const float* ifb = iface + (long)b * 512 * 714;
  float* wwb = ww_out + (long)b * 512 * 1024;
  u16* snb = snap + (long)b * 2097152;

  // preload interface row 0 slices
  float pre = 0.f;
  {
    const float* r0 = ifb;
    if (wid == 0) pre = r0[520 + lane];
    else if (wid == 1) pre = r0[585 + lane];
    else if (wid == 2) pre = r0[649 + lane];
    else if (wid == 3 && lane < 2) pre = r0[lane ? 713 : 584];
  }

  for (int t = 0; t < 512; ++t) {
    if ((t & 15) == 0) {
      u16* sr = snb + ((long)(t >> 4) * 1024 + tid) * 64;
      #pragma unroll
      for (int i = 0; i < 8; i++) {
        u16x8 o;
        #pragma unroll
        for (int j = 0; j < 8; j++) o[j] = f2bf(m[i * 8 + j]);
        *(u16x8*)(sr + i * 8) = o;
      }
    }
    __syncthreads();
    if (wid == 0) {
      s_wk[lane] = pre;
      float ss = wred_sum(pre * pre);
      if (!lane) s_aux[0] = rsqrtf(ss + 1e-8f);
    } else if (wid == 1) s_er[lane] = sigmoidf_(pre);
    else if (wid == 2) s_wv[lane] = pre;
    else if (wid == 3 && lane < 2) s_aux[1 + lane] = lane ? sigmoidf_(pre) : softplusf_(pre);
    // prefetch next row
    {
      int tn = (t + 1 < 512) ? t + 1 : 511;
      const float* rn = ifb + (long)tn * 714;
      if (wid == 0) pre = rn[520 + lane];
      else if (wid == 1) pre = rn[585 + lane];
      else if (wid == 2) pre = rn[649 + lane];
      else if (wid == 3 && lane < 2) pre = rn[lane ? 713 : 584];
    }
    __syncthreads();

    // norm + write dot (f32x4 -> packed fma)
    const f32x4* m4 = (const f32x4*)m;
    const f32x4* k4 = (const f32x4*)s_wk;
    f32x4 n4 = {1e-8f, 0.f, 0.f, 0.f};
    f32x4 d4 = {0.f, 0.f, 0.f, 0.f};
    #pragma unroll
    for (int i = 0; i < 16; i++) {
      f32x4 mv = m4[i], kv = k4[i];
      n4.x = __builtin_fmaf(mv.x, mv.x, n4.x); n4.y = __builtin_fmaf(mv.y, mv.y, n4.y);
      n4.z = __builtin_fmaf(mv.z, mv.z, n4.z); n4.w = __builtin_fmaf(mv.w, mv.w, n4.w);
      d4.x = __builtin_fmaf(kv.x, mv.x, d4.x); d4.y = __builtin_fmaf(kv.y, mv.y, d4.y);
      d4.z = __builtin_fmaf(kv.z, mv.z, d4.z); d4.w = __builtin_fmaf(kv.w, mv.w, d4.w);
    }
    float n2 = (n4.x + n4.y) + (n4.z + n4.w);
    float dot = (d4.x + d4.y) + (d4.z + d4.w);
    float ew = __expf(s_aux[1] * (dot * rsqrtf(n2) * s_aux[0]));
    float ssum = wred_sum(ew);
    if (!lane) s_red[wid] = ssum;
    __syncthreads();
    float tot;
    {
      const f32x4* rr = (const f32x4*)s_red;
      f32x4 a = rr[0], bq = rr[1], cq = rr[2], dq = rr[3];
      tot = ((a.x + a.y) + (a.z + a.w)) + ((bq.x + bq.y) + (bq.z + bq.w)) +
            ((cq.x + cq.y) + (cq.z + cq.w)) + ((dq.x + dq.y) + (dq.z + dq.w));
    }
    float ww = s_aux[2] * ew / tot;
    wwb[(long)t * 1024 + tid] = ww;

    // update M row
    f32x4* mw = (f32x4*)m;
    const f32x4* e4 = (const f32x4*)s_er;
    const f32x4* v4 = (const f32x4*)s_wv;
    #pragma unroll
    for (int i = 0; i < 16; i++) {
      f32x4 ev = e4[i], vv = v4[i], mv = mw[i];
      mv.x = __builtin_fmaf(ww, __builtin_fmaf(-ev.x, mv.x, vv.x), mv.x);
      mv.y = __builtin_fmaf(ww, __builtin_fmaf(-ev.y, mv.y, vv.y), mv.y);
      mv.z = __builtin_fmaf(ww, __builtin_fmaf(-ev.z, mv.z, vv.z), mv.z);
      mv.w = __builtin_fmaf(ww, __builtin_fmaf(-ev.w, mv.w, vv.w), mv.w);
      mw[i] = mv;
    }
  }
}

// ---------------- DNC pass 2: parallel read-path replay ----------------
// grid (8 batches, 32 chunks of 16 steps), 1024 threads.
#define P2_LDS 150624
__global__ __launch_bounds__(1024) void scan2_k(const float* __restrict__ iface,
                                                const float* __restrict__ ww_in,
                                                const u16* __restrict__ snap,
                                                float* __restrict__ out) {
  int b = blockIdx.x, c = blockIdx.y, tid = threadIdx.x, lane = tid & 63, wid = tid >> 6;
  extern __shared__ char smem[];
  u16* s_Mbf = (u16*)smem;               // 65536 u16 (bf16 M, XOR-swizzled 16B blocks)
  u16* s_rw = s_Mbf + 65536;             // 8192 u16 (read exps; reused for partials)
  float* s_rk = (float*)(s_rw + 8192);   // 512
  float* s_er = s_rk + 512;              // 64
  float* s_wv = s_er + 64;               // 64
  float* s_aux = s_wv + 64;              // 16: [0..7]=inv|rk|, [8..15]=rb
  float* s_red = s_aux + 16;             // 128
  float* s_tot = s_red + 128;            // 8

  float m[64];
  {
    const u16* sr = snap + (((long)b * 32 + c) * 1024 + tid) * 64;
    #pragma unroll
    for (int i = 0; i < 8; i++) {
      u16x8 v = *(const u16x8*)(sr + i * 8);
      #pragma unroll
      for (int j = 0; j < 8; j++) m[i * 8 + j] = bf2f(v[j]);
    }
  }
  const float* ifb = iface + (long)b * 512 * 714;
  const float* wwb = ww_in + (long)b * 512 * 1024;
  float* outb = out + (long)b * 512 * 512;
  int t0 = c * 16;

  float pre = 0.f;
  float wwreg = wwb[(long)t0 * 1024 + tid];
  {
    const float* r0 = ifb + (long)t0 * 714;
    if (wid >= 1 && wid <= 8) pre = r0[(wid - 1) * 64 + lane];
    else if (wid == 9) pre = r0[585 + lane];
    else if (wid == 10) pre = r0[649 + lane];
    else if (wid == 11 && lane < 8) pre = r0[512 + lane];
  }
  int n7 = tid & 7;

  for (int ti = 0; ti < 16; ++ti) {
    int t = t0 + ti;
    __syncthreads();
    if (wid >= 1 && wid <= 8) {
      int h = wid - 1;
      s_rk[h * 64 + lane] = pre;
      float ss = wred_sum(pre * pre);
      if (!lane) s_aux[h] = rsqrtf(ss + 1e-8f);
    } else if (wid == 9) s_er[lane] = sigmoidf_(pre);
    else if (wid == 10) s_wv[lane] = pre;
    else if (wid == 11 && lane < 8) s_aux[8 + lane] = softplusf_(pre);
    float ww = wwreg;
    // prefetch next step
    {
      int tn = (t + 1 < 512) ? t + 1 : 511;
      const float* rn = ifb + (long)tn * 714;
      if (wid >= 1 && wid <= 8) pre = rn[(wid - 1) * 64 + lane];
      else if (wid == 9) pre = rn[585 + lane];
      else if (wid == 10) pre = rn[649 + lane];
      else if (wid == 11 && lane < 8) pre = rn[512 + lane];
      wwreg = wwb[(long)tn * 1024 + tid];
    }
    __syncthreads();

    // update M row (stored ww => exact replay)
    f32x4* mw = (f32x4*)m;
    const f32x4* e4 = (const f32x4*)s_er;
    const f32x4* v4 = (const f32x4*)s_wv;
    #pragma unroll
    for (int i = 0; i < 16; i++) {
      f32x4 ev = e4[i], vv = v4[i], mv = mw[i];
      mv.x = __builtin_fmaf(ww, __builtin_fmaf(-ev.x, mv.x, vv.x), mv.x);
      mv.y = __builtin_fmaf(ww, __builtin_fmaf(-ev.y, mv.y, vv.y), mv.y);
      mv.z = __builtin_fmaf(ww, __builtin_fmaf(-ev.z, mv.z, vv.z), mv.z);
      mv.w = __builtin_fmaf(ww, __builtin_fmaf(-ev.w, mv.w, vv.w), mv.w);
      mw[i] = mv;
    }
    // write own row to LDS bf16 (swizzle 16B block index with row&7)
    #pragma unroll
    for (int i = 0; i < 8; i++) {
      u16x8 o;
      #pragma unroll
      for (int j = 0; j < 8; j++) o[j] = f2bf(m[i * 8 + j]);
      *(u16x8*)(s_Mbf + tid * 64 + ((i ^ n7) << 3)) = o;
    }
    // norm
    const f32x4* m4 = (const f32x4*)m;
    f32x4 n4 = {1e-8f, 0.f, 0.f, 0.f};
    #pragma unroll
    for (int i = 0; i < 16; i++) {
      f32x4 mv = m4[i];
      n4.x = __builtin_fmaf(mv.x, mv.x, n4.x); n4.y = __builtin_fmaf(mv.y, mv.y, n4.y);
      n4.z = __builtin_fmaf(mv.z, mv.z, n4.z); n4.w = __builtin_fmaf(mv.w, mv.w, n4.w);
    }
    float invm = rsqrtf((n4.x + n4.y) + (n4.z + n4.w));
    // 8 read dots + exp
    float eh[8];
    u16x8 ehb;
    #pragma unroll
    for (int h = 0; h < 8; h++) {
      const f32x4* kk = (const f32x4*)(s_rk + h * 64);
      f32x4 a = {0.f, 0.f, 0.f, 0.f};
      #pragma unroll
      for (int i = 0; i < 16; i++) {
        f32x4 kv = kk[i], mv = m4[i];
        a.x = __builtin_fmaf(kv.x, mv.x, a.x); a.y = __builtin_fmaf(kv.y, mv.y, a.y);
        a.z = __builtin_fmaf(kv.z, mv.z, a.z); a.w = __builtin_fmaf(kv.w, mv.w, a.w);
      }
      float d = (a.x + a.y) + (a.z + a.w);
      eh[h] = __expf(s_aux[8 + h] * (d * invm * s_aux[h]));
      ehb[h] = f2bf(eh[h]);
    }
    *(u16x8*)(s_rw + tid * 8) = ehb;
    #pragma unroll
    for (int h = 0; h < 8; h++) {
      float sh = wred_sum(eh[h]);
      if (!lane) s_red[wid * 8 + h] = sh;
    }
    __syncthreads();
    if (tid < 8) {
      float tt = 0.f;
      #pragma unroll
      for (int j = 0; j < 16; j++) tt += s_red[j * 8 + tid];
      s_tot[tid] = 1.f / tt;
    }
    // phase D: wave wid owns rows [wid*64, wid*64+64), all 8 heads, col = lane
    f32x2 r01 = {0.f, 0.f}, r23 = {0.f, 0.f}, r45 = {0.f, 0.f}, r67 = {0.f, 0.f};
    int rbase = wid << 6;
    int cblk = lane >> 3, cin = lane & 7;
    #pragma unroll 4
    for (int j = 0; j < 64; j++) {
      int row = rbase + j;
      float mf = bf2f(s_Mbf[row * 64 + ((cblk ^ (row & 7)) << 3) + cin]);
      u32x4 rr = *(const u32x4*)(s_rw + row * 8);
      f32x2 mf2 = {mf, mf};
      f32x2 p0 = {blo(rr.x), bhi(rr.x)};
      f32x2 p1 = {blo(rr.y), bhi(rr.y)};
      f32x2 p2 = {blo(rr.z), bhi(rr.z)};
      f32x2 p3 = {blo(rr.w), bhi(rr.w)};
      r01.x = __builtin_fmaf(mf2.x, p0.x, r01.x); r01.y = __builtin_fmaf(mf2.y, p0.y, r01.y);
      r23.x = __builtin_fmaf(mf2.x, p1.x, r23.x); r23.y = __builtin_fmaf(mf2.y, p1.y, r23.y);
      r45.x = __builtin_fmaf(mf2.x, p2.x, r45.x); r45.y = __builtin_fmaf(mf2.y, p2.y, r45.y);
      r67.x = __builtin_fmaf(mf2.x, p3.x, r67.x); r67.y = __builtin_fmaf(mf2.y, p3.y, r67.y);
    }
    __syncthreads();  // done reading s_rw / s_Mbf; s_tot ready
    // cross-wave partial reduce via bf16 partials in s_rw region
    {
      u16x8 o;
      o[0] = f2bf(r01.x); o[1] = f2bf(r01.y); o[2] = f2bf(r23.x); o[3] = f2bf(r23.y);
      o[4] = f2bf(r45.x); o[5] = f2bf(r45.y); o[6] = f2bf(r67.x); o[7] = f2bf(r67.y);
      *(u16x8*)(s_rw + (wid << 9) + (lane << 3)) = o;
    }
    __syncthreads();
    if (tid < 512) {
      int h = tid >> 6, ow = tid & 63;
      float s = 0.f;
      #pragma unroll
      for (int j = 0; j < 16; j++) s += bf2f(s_rw[(j << 9) + (ow << 3) + h]);
      outb[(long)t * 512 + tid] = s * s_tot[h];
    }
  }
}

// ---------------- host ----------------
static void launch_gemm(hipStream_t stream, const u16* A, int lda, const u16* B, int ldb,
                        const float* bias, float* oF, u16* oB, int ldc,
                        int M, int N, int K, int gz,
                        long sAb, long sAh, long sAz, long sBb, long sBh, long sBz,
                        long sCb, long sCh, long sCz, int zdiv, int z0, float alpha, int relu) {
  GemmP p;
  p.A = A; p.B = B; p.bias = bias; p.outF = oF; p.outB = oB;
  p.M = M; p.N = N; p.K = K; p.lda = lda; p.ldb = ldb; p.ldc = ldc;
  p.sAb = sAb; p.sAh = sAh; p.sAz = sAz;
  p.sBb = sBb; p.sBh = sBh; p.sBz = sBz;
  p.sCb = sCb; p.sCh = sCh; p.sCz = sCz;
  p.zdiv = zdiv; p.z0 = z0; p.alpha = alpha; p.relu = relu;
  dim3 g(M / 128, (N + 127) / 128, gz);
  gemm_k<<<g, 256, 0, stream>>>(p);
}

extern "C" void kernel_launch(void* const* d_in, const int* in_sizes, int n_in,
                              void* d_out, int out_size, void* d_ws, size_t ws_size,
                              hipStream_t stream) {
  (void)in_sizes; (void)n_in; (void)out_size; (void)ws_size;
  const float* x    = (const float*)d_in[0];
  const float* Wp   = (const float*)d_in[1];
  const float* bp   = (const float*)d_in[2];
  const float* Wqkv = (const float*)d_in[3];
  const float* bqkv = (const float*)d_in[4];
  const float* Wo   = (const float*)d_in[5];
  const float* bo   = (const float*)d_in[6];
  const float* ln1g = (const float*)d_in[7];
  const float* ln1b = (const float*)d_in[8];
  const float* W1   = (const float*)d_in[9];
  const float* b1   = (const float*)d_in[10];
  const float* W2   = (const float*)d_in[11];
  const float* b2   = (const float*)d_in[12];
  const float* ln2g = (const float*)d_in[13];
  const float* ln2b = (const float*)d_in[14];
  const float* Wi   = (const float*)d_in[15];
  const float* bi   = (const float*)d_in[16];
  const float* M0   = (const float*)d_in[17];
  float* outF = (float*)d_out;

  char* ws = (char*)d_ws;
  u16* WpT   = (u16*)ws;
  u16* WqkvT = WpT + 262144;
  u16* WoT   = WqkvT + 1572864;
  u16* W1T   = WoT + 524288;
  u16* W2T   = W1T + 2097152;
  u16* WiT   = W2T + 2097152;
  u16* xb    = WiT + 365568;
  u16* hb    = xb + 2097152;
  float* h   = (float*)(hb + 2097152);
  u16* qkvb  = (u16*)(h + 2097152);
  u16* vT    = qkvb + 6291456;
  float* scores = (float*)(vT + 2097152);
  u16* pbuf  = (u16*)(scores + 4194304);
  u16* obuf  = pbuf + 4194304;
  float* gout = (float*)(obuf + 2097152);
  u16* ffb   = (u16*)(gout + 2924544);
  float* ifbuf = (float*)(ffb + 8388608);
  // scan scratch (reuses buffers dead after the transformer):
  float* wwbuf = scores;      // 8*512*1024 f32 = 16 MB  (== scores region size)
  u16* snapb  = pbuf;         // 8*32*1024*64 bf16 = 32 MB (pbuf..ffb span = 39 MB)

  // casts / transposes
  castx_k<<<2048, 256, 0, stream>>>(x, xb, 524288);
  castT_k<<<dim3(1024, 1, 1), 256, 0, stream>>>(Wp, WpT, 512, 512);
  castT_k<<<dim3(3072, 1, 2), 256, 0, stream>>>(Wqkv, WqkvT, 512, 1536);
  castT_k<<<dim3(1024, 1, 2), 256, 0, stream>>>(Wo, WoT, 512, 512);
  castT_k<<<dim3(4096, 1, 2), 256, 0, stream>>>(W1, W1T, 512, 2048);
  castT_k<<<dim3(4096, 1, 2), 256, 0, stream>>>(W2, W2T, 2048, 512);
  castT_k<<<dim3(1428, 1, 1), 256, 0, stream>>>(Wi, WiT, 512, 714);

  // projection: h = x @ Wp + bp
  launch_gemm(stream, xb, 512, WpT, 512, bp, h, hb, 512, 4096, 512, 512,
              1, 0,0,0, 0,0,0, 0,0,0, 1, 0, 1.f, 0);

  for (int l = 0; l < 2; ++l) {
    launch_gemm(stream, hb, 512, WqkvT + (long)l * 786432, 512, bqkv + l * 1536,
                nullptr, qkvb, 1536, 4096, 1536, 512,
                1, 0,0,0, 0,0,0, 0,0,0, 1, 0, 1.f, 0);
    vtx_k<<<8192, 256, 0, stream>>>(qkvb, vT);
    for (int ch = 0; ch < 4; ++ch) {
      launch_gemm(stream, qkvb, 1536, qkvb + 512, 1536, nullptr, scores, nullptr, 512,
                  512, 512, 64, 16,
                  786432, 64, 0,  786432, 64, 0,  0, 0, 262144, 8, ch * 16, 0.125f, 0);
      smax_k<<<8192, 64, 0, stream>>>(scores, pbuf);
      launch_gemm(stream, pbuf, 512, vT, 512, nullptr, nullptr, obuf, 512,
                  512, 64, 512, 16,
                  0, 0, 262144,  262144, 32768, 0,  262144, 64, 0, 8, ch * 16, 1.f, 0);
    }
    launch_gemm(stream, obuf, 512, WoT + (long)l * 262144, 512, bo + l * 512,
                gout, nullptr, 512, 4096, 512, 512,
                1, 0,0,0, 0,0,0, 0,0,0, 1, 0, 1.f, 0);
    ln_k<<<4096, 64, 0, stream>>>(gout, h, ln1g + l * 512, ln1b + l * 512, h, hb);
    launch_gemm(stream, hb, 512, W1T + (long)l * 1048576, 512, b1 + l * 2048,
                nullptr, ffb, 2048, 4096, 2048, 512,
                1, 0,0,0, 0,0,0, 0,0,0, 1, 0, 1.f, 1);
    launch_gemm(stream, ffb, 2048, W2T + (long)l * 1048576, 2048, b2 + l * 512,
                gout, nullptr, 512, 4096, 512, 2048,
                1, 0,0,0, 0,0,0, 0,0,0, 1, 0, 1.f, 0);
    float* lnout = (l == 1) ? outF : h;
    ln_k<<<4096, 64, 0, stream>>>(gout, h, ln2g + l * 512, ln2b + l * 512, lnout, hb);
  }

  // iface = tout @ Wi + bi
  launch_gemm(stream, hb, 512, WiT, 512, bi, ifbuf, nullptr, 714,
              4096, 714, 512, 1, 0,0,0, 0,0,0, 0,0,0, 1, 0, 1.f, 0);

  // DNC: sequential write pass, then parallel read replay
  scan1_k<<<8, 1024, 0, stream>>>(ifbuf, M0, wwbuf, snapb);
  hipFuncSetAttribute(reinterpret_cast<const void*>(scan2_k),
                      hipFuncAttributeMaxDynamicSharedMemorySize, P2_LDS);
  scan2_k<<<dim3(8, 32), 1024, P2_LDS, stream>>>(ifbuf, wwbuf, snapb, outF + 2097152);
}

// Round 3
// 3078.531 us; speedup vs baseline: 3.6359x; 1.2040x over previous
//
#include <hip/hip_runtime.h>

typedef unsigned short u16;
typedef unsigned int u32;
typedef __attribute__((ext_vector_type(8))) short s16x8;
typedef __attribute__((ext_vector_type(8))) u16 u16x8;
typedef __attribute__((ext_vector_type(4))) u16 u16x4;
typedef __attribute__((ext_vector_type(4))) u32 u32x4;
typedef __attribute__((ext_vector_type(4))) float f32x4;
typedef __attribute__((ext_vector_type(2))) float f32x2;

#define L2E 1.4426950408889634f

__device__ __forceinline__ u16 f2bf(float f) {
  unsigned u = __builtin_bit_cast(unsigned, f);
  u = (u + 0x7fffu + ((u >> 16) & 1u)) >> 16;
  return (u16)u;
}
__device__ __forceinline__ float bf2f(u16 s) {
  unsigned u = ((unsigned)s) << 16;
  return __builtin_bit_cast(float, u);
}
__device__ __forceinline__ float blo(u32 d) { return __builtin_bit_cast(float, d << 16); }
__device__ __forceinline__ float bhi(u32 d) { return __builtin_bit_cast(float, d & 0xFFFF0000u); }
__device__ __forceinline__ float sigmoidf_(float x) { return 1.f / (1.f + __expf(-x)); }
__device__ __forceinline__ float softplusf_(float x) { return (x > 20.f) ? x : logf(1.f + __expf(x)); }

__device__ __forceinline__ float wred_sum(float v) {
  #pragma unroll
  for (int d = 1; d < 64; d <<= 1) v += __shfl_xor(v, d);
  return v;
}
__device__ __forceinline__ float wred_max(float v) {
  #pragma unroll
  for (int d = 1; d < 64; d <<= 1) v = fmaxf(v, __shfl_xor(v, d));
  return v;
}

// ---------------- cast kernels ----------------
__global__ void castx_k(const float* __restrict__ in, u16* __restrict__ out, int n4) {
  int i = blockIdx.x * 256 + threadIdx.x;
  if (i < n4) {
    f32x4 v = *(const f32x4*)(in + (long)i * 4);
    u16x4 o;
    o.x = f2bf(v.x); o.y = f2bf(v.y); o.z = f2bf(v.z); o.w = f2bf(v.w);
    *(u16x4*)(out + (long)i * 4) = o;
  }
}

// f32 (K,N) row-major -> bf16 (N,K) row-major, batched over z
__global__ void castT_k(const float* __restrict__ in, u16* __restrict__ out, int K, int N) {
  long base = (long)blockIdx.z * K * N;
  int idx = blockIdx.x * 256 + threadIdx.x;
  if (idx < K * N) {
    int n = idx / K, k = idx - n * K;
    out[base + idx] = f2bf(in[base + (long)k * N + n]);
  }
}

// extract transposed V: vT[(b,h)][d][s] = qkv[(b,s)][2H + h*64 + d]
__global__ void vtx_k(const u16* __restrict__ qkv, u16* __restrict__ vT) {
  int idx = blockIdx.x * 256 + threadIdx.x;
  int s = idx & 511;
  int d = (idx >> 9) & 63;
  int bh = idx >> 15;
  int b = bh >> 3, h = bh & 7;
  vT[idx] = qkv[((long)(b * 512 + s)) * 1536 + 1024 + h * 64 + d];
}

// ---------------- GEMM (bf16 MFMA, B passed as B^T = (N,K) row-major) ----------------
struct GemmP {
  const u16* A; const u16* B; const float* bias;
  float* outF; u16* outB;
  int M, N, K, lda, ldb, ldc;
  long sAb, sAh, sAz, sBb, sBh, sBz, sCb, sCh, sCz;
  int zdiv, z0;
  float alpha; int relu;
};

__global__ __launch_bounds__(256) void gemm_k(GemmP p) {
  __shared__ u16 sA[128 * 72];
  __shared__ u16 sB[128 * 72];
  int tid = threadIdx.x;
  int gp = p.z0 + blockIdx.z;
  int zb = gp / p.zdiv, zh = gp - zb * p.zdiv;
  const u16* Ab = p.A + zb * p.sAb + zh * p.sAh + (long)blockIdx.z * p.sAz + (long)blockIdx.x * 128 * p.lda;
  const u16* Bb = p.B + zb * p.sBb + zh * p.sBh + (long)blockIdx.z * p.sBz;
  long coff = zb * p.sCb + zh * p.sCh + (long)blockIdx.z * p.sCz;
  int bn = blockIdx.y * 128;
  int lane = tid & 63, wid = tid >> 6;
  int wr = wid >> 1, wc = wid & 1;

  f32x4 acc[4][4];
  f32x4 z4 = {0.f, 0.f, 0.f, 0.f};
  #pragma unroll
  for (int i = 0; i < 4; i++)
    #pragma unroll
    for (int j = 0; j < 4; j++) acc[i][j] = z4;

  int r = tid >> 1, c32 = (tid & 1) * 32;
  for (int k0 = 0; k0 < p.K; k0 += 64) {
    const u16* Ag = Ab + (long)r * p.lda + k0 + c32;
    u16x8* dA = (u16x8*)(sA + r * 72 + c32);
    #pragma unroll
    for (int i = 0; i < 4; i++) dA[i] = *(const u16x8*)(Ag + i * 8);
    int nrow = bn + r;
    u16x8* dB = (u16x8*)(sB + r * 72 + c32);
    if (nrow < p.N) {
      const u16* Bg = Bb + (long)nrow * p.ldb + k0 + c32;
      #pragma unroll
      for (int i = 0; i < 4; i++) dB[i] = *(const u16x8*)(Bg + i * 8);
    } else {
      u16x8 zz = (u16x8)0;
      #pragma unroll
      for (int i = 0; i < 4; i++) dB[i] = zz;
    }
    __syncthreads();
    #pragma unroll
    for (int ks = 0; ks < 2; ks++) {
      int ko = ks * 32 + (lane >> 4) * 8;
      s16x8 af[4], bf[4];
      #pragma unroll
      for (int m = 0; m < 4; m++) af[m] = *(const s16x8*)(sA + (wr * 64 + m * 16 + (lane & 15)) * 72 + ko);
      #pragma unroll
      for (int n = 0; n < 4; n++) bf[n] = *(const s16x8*)(sB + (wc * 64 + n * 16 + (lane & 15)) * 72 + ko);
      #pragma unroll
      for (int m = 0; m < 4; m++)
        #pragma unroll
        for (int n = 0; n < 4; n++)
          acc[m][n] = __builtin_amdgcn_mfma_f32_16x16x32_bf16(af[m], bf[n], acc[m][n], 0, 0, 0);
    }
    __syncthreads();
  }

  int row0 = blockIdx.x * 128 + wr * 64;
  int col0 = bn + wc * 64;
  #pragma unroll
  for (int n = 0; n < 4; n++) {
    int col = col0 + n * 16 + (lane & 15);
    if (col >= p.N) continue;
    float bv = p.bias ? p.bias[col] : 0.f;
    #pragma unroll
    for (int m = 0; m < 4; m++) {
      #pragma unroll
      for (int q = 0; q < 4; q++) {
        int row = row0 + m * 16 + (lane >> 4) * 4 + q;
        float v = acc[m][n][q] * p.alpha + bv;
        if (p.relu) v = fmaxf(v, 0.f);
        long ci = coff + (long)row * p.ldc + col;
        if (p.outF) p.outF[ci] = v;
        if (p.outB) p.outB[ci] = f2bf(v);
      }
    }
  }
}

// ---------------- fused residual + LayerNorm ----------------
__global__ __launch_bounds__(64) void ln_k(const float* __restrict__ a, const float* __restrict__ res,
                                           const float* __restrict__ g, const float* __restrict__ bb,
                                           float* __restrict__ outF, u16* __restrict__ outB) {
  int row = blockIdx.x, t = threadIdx.x;
  const float* ar = a + (long)row * 512;
  const float* rr = res + (long)row * 512;
  float x[8];
  float s1 = 0.f;
  #pragma unroll
  for (int i = 0; i < 8; i++) { x[i] = ar[i * 64 + t] + rr[i * 64 + t]; s1 += x[i]; }
  s1 = wred_sum(s1);
  float mean = s1 * (1.f / 512.f);
  float s2 = 0.f;
  #pragma unroll
  for (int i = 0; i < 8; i++) { float d = x[i] - mean; s2 += d * d; }
  s2 = wred_sum(s2);
  float inv = rsqrtf(s2 * (1.f / 512.f) + 1e-5f);
  #pragma unroll
  for (int i = 0; i < 8; i++) {
    int cc = i * 64 + t;
    float y = (x[i] - mean) * inv * g[cc] + bb[cc];
    outF[(long)row * 512 + cc] = y;
    outB[(long)row * 512 + cc] = f2bf(y);
  }
}

// ---------------- row softmax (512 cols) -> bf16 ----------------
__global__ __launch_bounds__(64) void smax_k(const float* __restrict__ s, u16* __restrict__ p) {
  long row = blockIdx.x;
  const float* sr = s + row * 512;
  int t = threadIdx.x;
  float v[8];
  float mx = -1e30f;
  #pragma unroll
  for (int i = 0; i < 8; i++) { v[i] = sr[i * 64 + t]; mx = fmaxf(mx, v[i]); }
  mx = wred_max(mx);
  float se = 0.f;
  #pragma unroll
  for (int i = 0; i < 8; i++) { v[i] = __expf(v[i] - mx); se += v[i]; }
  se = wred_sum(se);
  float inv = 1.f / se;
  u16* pr = p + row * 512;
  #pragma unroll
  for (int i = 0; i < 8; i++) pr[i * 64 + t] = f2bf(v[i] * inv);
}

// ---------------- DNC prep: fold norms/betas/log2e into keys, apply gates ----------------
// record (stride 712 f32): [0:64]=wk*(wb*log2e/|wk|), [64:128]=sigmoid(er),
// [128:192]=wv, [192:704]=rk_h*(rb_h*log2e/|rk_h|), [704]=gw
__global__ __launch_bounds__(256) void prep_k(const float* __restrict__ iface,
                                              float* __restrict__ rec) {
  int idx = blockIdx.x * 4 + (threadIdx.x >> 6);
  int lane = threadIdx.x & 63;
  const float* r = iface + (long)idx * 714;
  float* o = rec + (long)idx * 712;
  float wk = r[520 + lane];
  float s2k = wred_sum(wk * wk);
  float wb = softplusf_(r[584]);
  o[lane] = wk * (wb * L2E * rsqrtf(s2k + 1e-8f));
  o[64 + lane] = sigmoidf_(r[585 + lane]);
  o[128 + lane] = r[649 + lane];
  #pragma unroll
  for (int h = 0; h < 8; h++) {
    float rk = r[h * 64 + lane];
    float s2r = wred_sum(rk * rk);
    float rb = softplusf_(r[512 + h]);
    o[192 + h * 64 + lane] = rk * (rb * L2E * rsqrtf(s2r + 1e-8f));
  }
  if (!lane) o[704] = sigmoidf_(r[713]);
}

// ---------------- DNC pass 1: sequential write-path scan ----------------
// 8 blocks (one per batch), 1024 threads, thread n owns M row n (64 f32 VGPRs).
__global__ __launch_bounds__(1024, 4) void scan1_k(const float* __restrict__ rec,
                                                   const float* __restrict__ M0,
                                                   float* __restrict__ ww_out,
                                                   u16* __restrict__ snap) {
  int b = blockIdx.x, tid = threadIdx.x, lane = tid & 63, wid = tid >> 6;
  __shared__ float s_kev[2][208];   // [0:64]=k', [64:128]=e, [128:192]=v, [192]=gw
  __shared__ float s_red[2][16];
  float m[64];
  {
    const float* M0r = M0 + (long)tid * 64;
    #pragma unroll
    for (int i = 0; i < 16; i++) {
      f32x4 v = *(const f32x4*)(M0r + i * 4);
      m[i * 4 + 0] = v.x; m[i * 4 + 1] = v.y; m[i * 4 + 2] = v.z; m[i * 4 + 3] = v.w;
    }
  }
  const float* rb_ = rec + (long)b * 512 * 712;
  float* wwb = ww_out + (long)b * 512 * 1024;
  u16* snb = snap + (long)b * 2097152;

  f32x4 pf = {0.f, 0.f, 0.f, 0.f};
  float gwp = 0.f;
  if (tid < 48) pf = *(const f32x4*)(rb_ + tid * 4);
  else if (tid == 48) gwp = rb_[704];

  for (int t = 0; t < 512; ++t) {
    int cb = t & 1;
    if ((t & 15) == 0) {
      u16* sr = snb + ((long)(t >> 4) * 1024 + tid) * 64;
      #pragma unroll
      for (int i = 0; i < 8; i++) {
        u16x8 o;
        #pragma unroll
        for (int j = 0; j < 8; j++) o[j] = f2bf(m[i * 8 + j]);
        *(u16x8*)(sr + i * 8) = o;
      }
    }
    if (tid < 48) *(f32x4*)&s_kev[cb][tid * 4] = pf;
    else if (tid == 48) s_kev[cb][192] = gwp;
    {
      const float* rn = rb_ + (long)(t + 1 < 512 ? t + 1 : 511) * 712;
      if (tid < 48) pf = *(const f32x4*)(rn + tid * 4);
      else if (tid == 48) gwp = rn[704];
    }
    __syncthreads();

    const f32x4* m4 = (const f32x4*)m;
    const f32x4* k4 = (const f32x4*)&s_kev[cb][0];
    f32x4 n4 = {1e-8f, 0.f, 0.f, 0.f};
    f32x4 d4 = {0.f, 0.f, 0.f, 0.f};
    #pragma unroll
    for (int i = 0; i < 16; i++) {
      f32x4 mv = m4[i], kv = k4[i];
      n4.x = __builtin_fmaf(mv.x, mv.x, n4.x); n4.y = __builtin_fmaf(mv.y, mv.y, n4.y);
      n4.z = __builtin_fmaf(mv.z, mv.z, n4.z); n4.w = __builtin_fmaf(mv.w, mv.w, n4.w);
      d4.x = __builtin_fmaf(kv.x, mv.x, d4.x); d4.y = __builtin_fmaf(kv.y, mv.y, d4.y);
      d4.z = __builtin_fmaf(kv.z, mv.z, d4.z); d4.w = __builtin_fmaf(kv.w, mv.w, d4.w);
    }
    float n2 = (n4.x + n4.y) + (n4.z + n4.w);
    float dot = (d4.x + d4.y) + (d4.z + d4.w);
    float ew = __builtin_amdgcn_exp2f(dot * rsqrtf(n2));
    float ssum = wred_sum(ew);
    if (!lane) s_red[cb][wid] = ssum;
    __syncthreads();
    float tot;
    {
      const f32x4* rr = (const f32x4*)&s_red[cb][0];
      f32x4 a = rr[0], bq = rr[1], cq = rr[2], dq = rr[3];
      tot = ((a.x + a.y) + (a.z + a.w)) + ((bq.x + bq.y) + (bq.z + bq.w)) +
            ((cq.x + cq.y) + (cq.z + cq.w)) + ((dq.x + dq.y) + (dq.z + dq.w));
    }
    float ww = s_kev[cb][192] * ew * __builtin_amdgcn_rcpf(tot);
    wwb[(long)t * 1024 + tid] = ww;

    f32x4* mw = (f32x4*)m;
    const f32x4* e4 = (const f32x4*)&s_kev[cb][64];
    const f32x4* v4 = (const f32x4*)&s_kev[cb][128];
    #pragma unroll
    for (int i = 0; i < 16; i++) {
      f32x4 ev = e4[i], vv = v4[i], mv = mw[i];
      mv.x = __builtin_fmaf(ww, __builtin_fmaf(-ev.x, mv.x, vv.x), mv.x);
      mv.y = __builtin_fmaf(ww, __builtin_fmaf(-ev.y, mv.y, vv.y), mv.y);
      mv.z = __builtin_fmaf(ww, __builtin_fmaf(-ev.z, mv.z, vv.z), mv.z);
      mv.w = __builtin_fmaf(ww, __builtin_fmaf(-ev.w, mv.w, vv.w), mv.w);
      mw[i] = mv;
    }
  }
}

// ---------------- DNC pass 2: parallel read-path replay ----------------
// grid (8 batches, 32 chunks of 16 steps), 1024 threads.
#define P2_LDS 153600
__global__ __launch_bounds__(1024, 4) void scan2_k(const float* __restrict__ rec,
                                                   const float* __restrict__ ww_in,
                                                   const u16* __restrict__ snap,
                                                   float* __restrict__ out) {
  int b = blockIdx.x, c = blockIdx.y, tid = threadIdx.x, lane = tid & 63, wid = tid >> 6;
  extern __shared__ char smem[];
  u16* s_Mbf = (u16*)smem;                    // 65536 u16 (128KB), bf16 M swizzled; per-wave 2KB head also reused for f32 partials
  float* s_kev = (float*)(s_Mbf + 65536);     // 2*640: [0:64]=e, [64:128]=v, [128:640]=rk'
  u16* s_rw = (u16*)(s_kev + 1280);           // 8192 u16 (swizzled 16B blocks)
  float* s_red = (float*)(s_rw + 8192);       // 2*128

  float m[64];
  {
    const u16* sr = snap + (((long)b * 32 + c) * 1024 + tid) * 64;
    #pragma unroll
    for (int i = 0; i < 8; i++) {
      u16x8 v = *(const u16x8*)(sr + i * 8);
      #pragma unroll
      for (int j = 0; j < 8; j++) m[i * 8 + j] = bf2f(v[j]);
    }
  }
  const float* rb_ = rec + (long)b * 512 * 712;
  const float* wwb = ww_in + (long)b * 512 * 1024;
  float* outb = out + (long)b * 512 * 512;
  int t0 = c * 16;
  int n7 = tid & 7;
  int blkswz = tid ^ ((tid >> 3) & 7);

  f32x4 pf = {0.f, 0.f, 0.f, 0.f};
  if (tid < 160) pf = *(const f32x4*)(rb_ + (long)t0 * 712 + 64 + tid * 4);
  float wwreg = wwb[(long)t0 * 1024 + tid];

  for (int ti = 0; ti < 16; ++ti) {
    int t = t0 + ti, cb = ti & 1;
    if (tid < 160) *(f32x4*)&s_kev[cb * 640 + tid * 4] = pf;
    float ww = wwreg;
    {
      int tn = (t + 1 < 512) ? t + 1 : 511;
      if (tid < 160) pf = *(const f32x4*)(rb_ + (long)tn * 712 + 64 + tid * 4);
      wwreg = wwb[(long)tn * 1024 + tid];
    }
    __syncthreads();  // A: prior phase-D/partial reads done; kev staged

    // replay M update
    f32x4* mw = (f32x4*)m;
    const f32x4* e4 = (const f32x4*)&s_kev[cb * 640];
    const f32x4* v4 = (const f32x4*)&s_kev[cb * 640 + 64];
    #pragma unroll
    for (int i = 0; i < 16; i++) {
      f32x4 ev = e4[i], vv = v4[i], mv = mw[i];
      mv.x = __builtin_fmaf(ww, __builtin_fmaf(-ev.x, mv.x, vv.x), mv.x);
      mv.y = __builtin_fmaf(ww, __builtin_fmaf(-ev.y, mv.y, vv.y), mv.y);
      mv.z = __builtin_fmaf(ww, __builtin_fmaf(-ev.z, mv.z, vv.z), mv.z);
      mv.w = __builtin_fmaf(ww, __builtin_fmaf(-ev.w, mv.w, vv.w), mv.w);
      mw[i] = mv;
    }
    // own row -> LDS bf16 (16B-block swizzle within the 128B row)
    #pragma unroll
    for (int i = 0; i < 8; i++) {
      u16x8 o;
      #pragma unroll
      for (int j = 0; j < 8; j++) o[j] = f2bf(m[i * 8 + j]);
      *(u16x8*)(s_Mbf + tid * 64 + ((i ^ n7) << 3)) = o;
    }
    // norm
    const f32x4* m4 = (const f32x4*)m;
    f32x4 n4 = {1e-8f, 0.f, 0.f, 0.f};
    #pragma unroll
    for (int i = 0; i < 16; i++) {
      f32x4 mv = m4[i];
      n4.x = __builtin_fmaf(mv.x, mv.x, n4.x); n4.y = __builtin_fmaf(mv.y, mv.y, n4.y);
      n4.z = __builtin_fmaf(mv.z, mv.z, n4.z); n4.w = __builtin_fmaf(mv.w, mv.w, n4.w);
    }
    float invm = rsqrtf((n4.x + n4.y) + (n4.z + n4.w));
    // 8 read dots (keys pre-scaled) + exp2
    float eh[8];
    u16x8 ehb;
    #pragma unroll
    for (int h = 0; h < 8; h++) {
      const f32x4* kk = (const f32x4*)&s_kev[cb * 640 + 128 + h * 64];
      f32x4 a = {0.f, 0.f, 0.f, 0.f};
      #pragma unroll
      for (int i = 0; i < 16; i++) {
        f32x4 kv = kk[i], mv = m4[i];
        a.x = __builtin_fmaf(kv.x, mv.x, a.x); a.y = __builtin_fmaf(kv.y, mv.y, a.y);
        a.z = __builtin_fmaf(kv.z, mv.z, a.z); a.w = __builtin_fmaf(kv.w, mv.w, a.w);
      }
      float d = (a.x + a.y) + (a.z + a.w);
      eh[h] = __builtin_amdgcn_exp2f(d * invm);
      ehb[h] = f2bf(eh[h]);
    }
    *(u16x8*)(s_rw + (blkswz << 3)) = ehb;
    #pragma unroll
    for (int h = 0; h < 8; h++) {
      float sh = wred_sum(eh[h]);
      if (!lane) s_red[cb * 128 + wid * 8 + h] = sh;
    }
    __syncthreads();  // B: s_rw + s_red + Mbf visible

    // phase D: wave wid sums its 64 rows for all 8 heads; lane = word
    float p[8];
    #pragma unroll
    for (int h = 0; h < 8; h++) p[h] = 0.f;
    int rbase = wid << 6;
    int cblk = lane >> 3, cin = lane & 7;
    #pragma unroll 4
    for (int j = 0; j < 64; j++) {
      int r = rbase + j;
      float mf = bf2f(s_Mbf[(r << 6) + (((cblk ^ r) & 7) << 3) + cin]);
      int rsw = r ^ ((r >> 3) & 7);
      u32x4 rr = *(const u32x4*)(s_rw + (rsw << 3));
      p[0] = __builtin_fmaf(mf, blo(rr.x), p[0]); p[1] = __builtin_fmaf(mf, bhi(rr.x), p[1]);
      p[2] = __builtin_fmaf(mf, blo(rr.y), p[2]); p[3] = __builtin_fmaf(mf, bhi(rr.y), p[3]);
      p[4] = __builtin_fmaf(mf, blo(rr.z), p[4]); p[5] = __builtin_fmaf(mf, bhi(rr.z), p[5]);
      p[6] = __builtin_fmaf(mf, blo(rr.w), p[6]); p[7] = __builtin_fmaf(mf, bhi(rr.w), p[7]);
    }
    // f32 partials into this wave's own (already-consumed) Mbf slice
    {
      float* pb = (float*)(s_Mbf + (wid << 12));
      #pragma unroll
      for (int h = 0; h < 8; h++) pb[h * 64 + lane] = p[h];
    }
    __syncthreads();  // C: partials ready

    if (tid < 512) {
      int h = tid >> 6, ow = tid & 63;
      float s = 0.f;
      #pragma unroll
      for (int j = 0; j < 16; j++) s += ((const float*)(s_Mbf + (j << 12)))[h * 64 + ow];
      float tt = 0.f;
      #pragma unroll
      for (int j = 0; j < 16; j++) tt += s_red[cb * 128 + j * 8 + h];
      outb[(long)t * 512 + tid] = s * __builtin_amdgcn_rcpf(tt);
    }
  }
}

// ---------------- host ----------------
static void launch_gemm(hipStream_t stream, const u16* A, int lda, const u16* B, int ldb,
                        const float* bias, float* oF, u16* oB, int ldc,
                        int M, int N, int K, int gz,
                        long sAb, long sAh, long sAz, long sBb, long sBh, long sBz,
                        long sCb, long sCh, long sCz, int zdiv, int z0, float alpha, int relu) {
  GemmP p;
  p.A = A; p.B = B; p.bias = bias; p.outF = oF; p.outB = oB;
  p.M = M; p.N = N; p.K = K; p.lda = lda; p.ldb = ldb; p.ldc = ldc;
  p.sAb = sAb; p.sAh = sAh; p.sAz = sAz;
  p.sBb = sBb; p.sBh = sBh; p.sBz = sBz;
  p.sCb = sCb; p.sCh = sCh; p.sCz = sCz;
  p.zdiv = zdiv; p.z0 = z0; p.alpha = alpha; p.relu = relu;
  dim3 g(M / 128, (N + 127) / 128, gz);
  gemm_k<<<g, 256, 0, stream>>>(p);
}

extern "C" void kernel_launch(void* const* d_in, const int* in_sizes, int n_in,
                              void* d_out, int out_size, void* d_ws, size_t ws_size,
                              hipStream_t stream) {
  (void)in_sizes; (void)n_in; (void)out_size; (void)ws_size;
  const float* x    = (const float*)d_in[0];
  const float* Wp   = (const float*)d_in[1];
  const float* bp   = (const float*)d_in[2];
  const float* Wqkv = (const float*)d_in[3];
  const float* bqkv = (const float*)d_in[4];
  const float* Wo   = (const float*)d_in[5];
  const float* bo   = (const float*)d_in[6];
  const float* ln1g = (const float*)d_in[7];
  const float* ln1b = (const float*)d_in[8];
  const float* W1   = (const float*)d_in[9];
  const float* b1   = (const float*)d_in[10];
  const float* W2   = (const float*)d_in[11];
  const float* b2   = (const float*)d_in[12];
  const float* ln2g = (const float*)d_in[13];
  const float* ln2b = (const float*)d_in[14];
  const float* Wi   = (const float*)d_in[15];
  const float* bi   = (const float*)d_in[16];
  const float* M0   = (const float*)d_in[17];
  float* outF = (float*)d_out;

  char* ws = (char*)d_ws;
  u16* WpT   = (u16*)ws;
  u16* WqkvT = WpT + 262144;
  u16* WoT   = WqkvT + 1572864;
  u16* W1T   = WoT + 524288;
  u16* W2T   = W1T + 2097152;
  u16* WiT   = W2T + 2097152;
  u16* xb    = WiT + 365568;
  u16* hb    = xb + 2097152;
  float* h   = (float*)(hb + 2097152);
  u16* qkvb  = (u16*)(h + 2097152);
  u16* vT    = qkvb + 6291456;
  float* scores = (float*)(vT + 2097152);
  u16* pbuf  = (u16*)(scores + 4194304);
  u16* obuf  = pbuf + 4194304;
  float* gout = (float*)(obuf + 2097152);
  u16* ffb   = (u16*)(gout + 2924544);
  float* ifbuf = (float*)(ffb + 8388608);
  // scan scratch (regions dead after the transformer):
  float* prepb = (float*)qkvb;  // 8*512*712 f32 = 11.67 MB <= qkvb 12 MB
  float* wwbuf = scores;        // 16 MB
  u16* snapb  = pbuf;           // 32 MB (spans pbuf/obuf/gout/ffb-head, all dead)

  // casts / transposes
  castx_k<<<2048, 256, 0, stream>>>(x, xb, 524288);
  castT_k<<<dim3(1024, 1, 1), 256, 0, stream>>>(Wp, WpT, 512, 512);
  castT_k<<<dim3(3072, 1, 2), 256, 0, stream>>>(Wqkv, WqkvT, 512, 1536);
  castT_k<<<dim3(1024, 1, 2), 256, 0, stream>>>(Wo, WoT, 512, 512);
  castT_k<<<dim3(4096, 1, 2), 256, 0, stream>>>(W1, W1T, 512, 2048);
  castT_k<<<dim3(4096, 1, 2), 256, 0, stream>>>(W2, W2T, 2048, 512);
  castT_k<<<dim3(1428, 1, 1), 256, 0, stream>>>(Wi, WiT, 512, 714);

  // projection: h = x @ Wp + bp
  launch_gemm(stream, xb, 512, WpT, 512, bp, h, hb, 512, 4096, 512, 512,
              1, 0,0,0, 0,0,0, 0,0,0, 1, 0, 1.f, 0);

  for (int l = 0; l < 2; ++l) {
    launch_gemm(stream, hb, 512, WqkvT + (long)l * 786432, 512, bqkv + l * 1536,
                nullptr, qkvb, 1536, 4096, 1536, 512,
                1, 0,0,0, 0,0,0, 0,0,0, 1, 0, 1.f, 0);
    vtx_k<<<8192, 256, 0, stream>>>(qkvb, vT);
    for (int ch = 0; ch < 4; ++ch) {
      launch_gemm(stream, qkvb, 1536, qkvb + 512, 1536, nullptr, scores, nullptr, 512,
                  512, 512, 64, 16,
                  786432, 64, 0,  786432, 64, 0,  0, 0, 262144, 8, ch * 16, 0.125f, 0);
      smax_k<<<8192, 64, 0, stream>>>(scores, pbuf);
      launch_gemm(stream, pbuf, 512, vT, 512, nullptr, nullptr, obuf, 512,
                  512, 64, 512, 16,
                  0, 0, 262144,  262144, 32768, 0,  262144, 64, 0, 8, ch * 16, 1.f, 0);
    }
    launch_gemm(stream, obuf, 512, WoT + (long)l * 262144, 512, bo + l * 512,
                gout, nullptr, 512, 4096, 512, 512,
                1, 0,0,0, 0,0,0, 0,0,0, 1, 0, 1.f, 0);
    ln_k<<<4096, 64, 0, stream>>>(gout, h, ln1g + l * 512, ln1b + l * 512, h, hb);
    launch_gemm(stream, hb, 512, W1T + (long)l * 1048576, 512, b1 + l * 2048,
                nullptr, ffb, 2048, 4096, 2048, 512,
                1, 0,0,0, 0,0,0, 0,0,0, 1, 0, 1.f, 1);
    launch_gemm(stream, ffb, 2048, W2T + (long)l * 1048576, 2048, b2 + l * 512,
                gout, nullptr, 512, 4096, 512, 2048,
                1, 0,0,0, 0,0,0, 0,0,0, 1, 0, 1.f, 0);
    float* lnout = (l == 1) ? outF : h;
    ln_k<<<4096, 64, 0, stream>>>(gout, h, ln2g + l * 512, ln2b + l * 512, lnout, hb);
  }

  // iface = tout @ Wi + bi
  launch_gemm(stream, hb, 512, WiT, 512, bi, ifbuf, nullptr, 714,
              4096, 714, 512, 1, 0,0,0, 0,0,0, 0,0,0, 1, 0, 1.f, 0);

  // DNC: prep (fold norms/betas), sequential write pass, parallel read replay
  prep_k<<<1024, 256, 0, stream>>>(ifbuf, prepb);
  scan1_k<<<8, 1024, 0, stream>>>(prepb, M0, wwbuf, snapb);
  hipFuncSetAttribute(reinterpret_cast<const void*>(scan2_k),
                      hipFuncAttributeMaxDynamicSharedMemorySize, P2_LDS);
  scan2_k<<<dim3(8, 32), 1024, P2_LDS, stream>>>(prepb, wwbuf, snapb, outF + 2097152);
}